// Round 29
// baseline (137.178 us; speedup 1.0000x reference)
//
#include <hip/hip_runtime.h>

#define B_    32
#define N_    256
#define H_    6
#define HD_   32
#define C_    192
#define C4_   768
#define TKIN  64
#define TKOUT 32
#define WULP  32u   // fast-path safety window (ulps on a32)
#define WPB   16    // waves per block (1024 threads)

// ---------------------------------------------------------------------------
// Kernel A (R26-PASS per-wave code, 16 waves/block): one wave per (b,h,i) row.
// Per-thread semantics byte-identical to R26; only block geometry changed
// (block-slot-limited occupancy theory: more waves per scarce block slot).
//  - canonical f32 chain -> a32 (values); q wave-uniform -> SGPR loads
//  - u64 packed-key rank (a32 desc, slot asc) via v_cmp_gt_u64
//  - O(1) near detect (sorted adjacency <=32 ulp) -> rare f64 okey slow path
// ---------------------------------------------------------------------------
__global__ __launch_bounds__(1024) void attn_topk_kernel(
    const float* __restrict__ qkvp,
    const float* __restrict__ pfa_values,
    const int*   __restrict__ pfa_index,
    const int*   __restrict__ rpi,
    const float* __restrict__ rpb_table,
    float* __restrict__ x_pre,
    float* __restrict__ out_topv,
    float* __restrict__ out_nidx)
{
    const int lane  = threadIdx.x & 63;
    const int wslot = threadIdx.x >> 6;                   // 0..15
    const int row   = blockIdx.x * WPB + wslot;
    const int b   = row / (H_ * N_);
    const int rem = row - b * (H_ * N_);
    const int h   = rem / N_;
    const int i   = rem - h * N_;

    const int row_off = row * TKIN;
    const int idx  = pfa_index[row_off + lane];
    const float pv = pfa_values[row_off + lane];

    __shared__ uint2  s_pk[WPB][64];    // packed (bits<<6)|(63-lane)
    __shared__ double s_k64[WPB][64];   // okey (slow path only)
    __shared__ float  s_a[WPB][TKOUT];
    __shared__ int    s_i[WPB][TKOUT];

    const float* qp = qkvp + (size_t)(b * N_ + i) * C4_ + h * HD_;
    const float* kp = qkvp + (size_t)(b * N_ + idx) * C4_ + C_ + h * HD_;
    const float bias = rpb_table[rpi[i * N_ + idx] * H_ + h];

    // ---- f32 chain: sequential no-FMA dot (bit-exact canonical) ----
    float acc;
    {
        #pragma clang fp contract(off)
        const float SC = 0.17677669529663687f;
        acc = 0.f;
        for (int d = 0; d < HD_; ++d) {
            const float qd   = qp[d] * SC;
            const float prod = qd * kp[d];
            acc = acc + prod;
        }
        acc = acc + bias;
    }

    // ---- f32 row max (exact, order-independent) ----
    float m = acc;
    #pragma unroll
    for (int s = 32; s; s >>= 1) m = fmaxf(m, __shfl_xor(m, s));

    // ---- e = exp(acc - m), correctly-rounded f32 via double ----
    float e;
    {
        #pragma clang fp contract(off)
        const float t = acc - m;
        e = (float)exp((double)t);
    }

    // ---- ssum: numpy pairwise-8 via shuffles (bit-exact, R22) ----
    float ssum;
    {
        #pragma clang fp contract(off)
        float y = e, r = e;
        #pragma unroll
        for (int k = 1; k < 8; ++k) { y = __shfl_down(y, 8); r = r + y; }
        const float t1 = r  + __shfl_xor(r, 1);
        const float t2 = t1 + __shfl_xor(t1, 2);
        const float t3 = t2 + __shfl_xor(t2, 4);
        ssum = __shfl(t3, 0);
    }

    // ---- w = (e/ssum)*pv ----
    float w;
    {
        #pragma clang fp contract(off)
        const float s32 = e / ssum;
        w = s32 * pv;
    }

    // ---- denom: same shuffle pairwise-8 over w ----
    float denom;
    {
        #pragma clang fp contract(off)
        float y = w, r = w;
        #pragma unroll
        for (int k = 1; k < 8; ++k) { y = __shfl_down(y, 8); r = r + y; }
        const float t1 = r  + __shfl_xor(r, 1);
        const float t2 = t1 + __shfl_xor(t1, 2);
        const float t3 = t2 + __shfl_xor(t2, 4);
        denom = __shfl(t3, 0);
    }

    // ---- a32 = (w + EPS)/(denom + EPS) ----
    float a32;
    {
        #pragma clang fp contract(off)
        a32 = (w + 1e-20f) / (denom + 1e-20f);
    }

    // ---- publish packed key ----
    const unsigned abits = __float_as_uint(a32);
    const unsigned long long myK =
        ((unsigned long long)abits << 6) | (unsigned long long)(63 - lane);
    s_pk[wslot][lane] = make_uint2((unsigned)myK, (unsigned)(myK >> 32));
    // no barrier: per-wave LDS slice; lgkmcnt orders RAW within the wave

    // ---- pass 1: rank via single u64 compare per j ----
    int rank = 0;
    #pragma unroll
    for (int j = 0; j < 64; ++j) {
        const uint2 kj = s_pk[wslot][j];
        const unsigned long long K =
            ((unsigned long long)kj.y << 32) | (unsigned long long)kj.x;
        rank += (K > myK);
    }

    // ---- near detect: sorted adjacency via ds_permute ----
    {
        const int sorted = __builtin_amdgcn_ds_permute(rank << 2, (int)abits);
        const int nxt    = __shfl_down(sorted, 1);
        const unsigned gap = (unsigned)sorted - (unsigned)nxt;   // descending
        const bool nearf = (lane < 63) && (gap <= WULP);
        if (__any(nearf)) {
            // ---- slow path (rare): okey comparator (R20/R25 verbatim) ----
            double acc64 = 0.0;
            #pragma unroll
            for (int d0 = 0; d0 < 8; ++d0) {
                const float4 q4 = *(const float4*)(qp + 4 * d0);
                const float4 k4 = *(const float4*)(kp + 4 * d0);
                acc64 = fma((double)q4.x, (double)k4.x, acc64);
                acc64 = fma((double)q4.y, (double)k4.y, acc64);
                acc64 = fma((double)q4.z, (double)k4.z, acc64);
                acc64 = fma((double)q4.w, (double)k4.w, acc64);
            }
            acc64 = acc64 * 0.17677669529663687 + (double)bias;
            const double okey = exp(acc64) * (double)pv;
            s_k64[wslot][lane] = okey;

            rank = 0;
            #pragma unroll
            for (int j = 0; j < 64; ++j) {
                const uint2 kj = s_pk[wslot][j];
                const unsigned kbits = (kj.y << 26) | (kj.x >> 6);
                const float  kj32 = __uint_as_float(kbits);
                const double kj64 = s_k64[wslot][j];
                const bool tie  = (kj32 == a32);
                const bool lt64 = (kj64 < okey);
                const bool gt64 = (kj64 > okey);
                const bool eq64 = (kj64 == okey);
                const bool before = tie ? (lt64 || (eq64 && j < lane))
                                        : (gt64 || (eq64 && kj32 > a32));
                rank += before;
            }
        }
    }

    if (rank < TKOUT) {
        const size_t obase = (size_t)row * TKOUT + rank;
        out_topv[obase] = a32;
        out_nidx[obase] = (float)idx;
        s_a[wslot][rank] = a32;
        s_i[wslot][rank] = idx;
    }

    // ---- PV (broadcast reads of own wave's compacted slots) ----
    const int d    = lane & 31;
    const int half = lane >> 5;
    float xd = 0.f;
    #pragma unroll
    for (int s16 = 0; s16 < 16; ++s16) {
        const int sI = half * 16 + s16;
        const float av = s_a[wslot][sI];
        const int   vi = s_i[wslot][sI];
        xd += av * qkvp[(size_t)(b * N_ + vi) * C4_ + 2 * C_ + h * HD_ + d];
    }
    xd += __shfl_xor(xd, 32);
    if (half == 0) {
        const float lepe = qkvp[(size_t)(b * N_ + i) * C4_ + 3 * C_ + h * HD_ + d];
        x_pre[(size_t)(b * N_ + i) * C_ + h * HD_ + d] = xd + lepe;
    }
}

// ---------------------------------------------------------------------------
#define TB_ 8
__global__ __launch_bounds__(192) void proj_kernel(
    const float* __restrict__ x_pre,
    const float* __restrict__ w,
    const float* __restrict__ bias,
    float* __restrict__ out)
{
    __shared__ float xs[TB_ * C_];
    const int o    = threadIdx.x;
    const int tok0 = blockIdx.x * TB_;

    #pragma unroll
    for (int r = 0; r < TB_; ++r)
        xs[r * C_ + o] = x_pre[(size_t)(tok0 + r) * C_ + o];
    __syncthreads();

    float accv[TB_];
    #pragma unroll
    for (int t = 0; t < TB_; ++t) accv[t] = 0.f;

    const float* wrow = w + (size_t)o * C_;
    for (int c = 0; c < C_; c += 4) {
        const float4 wv = *(const float4*)(wrow + c);
        #pragma unroll
        for (int t = 0; t < TB_; ++t) {
            const float4 xv = *(const float4*)(&xs[t * C_ + c]);
            accv[t] += xv.x * wv.x + xv.y * wv.y + xv.z * wv.z + xv.w * wv.w;
        }
    }
    const float bo = bias[o];
    #pragma unroll
    for (int t = 0; t < TB_; ++t)
        out[(size_t)(tok0 + t) * C_ + o] = accv[t] + bo;
}

// ---------------------------------------------------------------------------
extern "C" void kernel_launch(void* const* d_in, const int* in_sizes, int n_in,
                              void* d_out, int out_size, void* d_ws, size_t ws_size,
                              hipStream_t stream) {
    const float* qkvp       = (const float*)d_in[0];
    const float* pfa_values = (const float*)d_in[1];
    const int*   pfa_index  = (const int*)d_in[2];
    const int*   rpi        = (const int*)d_in[3];
    const float* rpb_table  = (const float*)d_in[4];
    const float* proj_w     = (const float*)d_in[5];
    const float* proj_b     = (const float*)d_in[6];

    float* out = (float*)d_out;
    float* out_x    = out;
    float* out_topv = out + (size_t)B_ * N_ * C_;
    float* out_nidx = out_topv + (size_t)B_ * H_ * N_ * TKOUT;

    float* x_pre = (float*)d_ws;

    const int rows = B_ * H_ * N_;                       // 49152
    attn_topk_kernel<<<rows / WPB, WPB * 64, 0, stream>>>(
        qkvp, pfa_values, pfa_index, rpi, rpb_table, x_pre, out_topv, out_nidx);

    const int ntok = B_ * N_;                            // 8192
    proj_kernel<<<ntok / TB_, 192, 0, stream>>>(x_pre, proj_w, proj_b, out_x);
}

// Round 30
// 114.271 us; speedup vs baseline: 1.2005x; 1.2005x over previous
//
#include <hip/hip_runtime.h>

#define B_    32
#define N_    256
#define H_    6
#define HD_   32
#define C_    192
#define C4_   768
#define TKIN  64
#define TKOUT 32
#define WULP  32u   // fast-path safety window (ulps on a32)

// ---------------------------------------------------------------------------
// Kernel A (R26-PASS + XCD-aware window clustering): one wave per row.
// Work permutation only: launch block n -> XCD x=n%8 (HW round-robin, m09);
// assign b = x*4 + (n/8)/384 so each XCD serves 4 windows -> k/v/q/rpi reuse
// set ~3.4MB fits its private 4MB L2. Per-wave code byte-identical to R26.
// ---------------------------------------------------------------------------
__global__ __launch_bounds__(256) void attn_topk_kernel(
    const float* __restrict__ qkvp,
    const float* __restrict__ pfa_values,
    const int*   __restrict__ pfa_index,
    const int*   __restrict__ rpi,
    const float* __restrict__ rpb_table,
    float* __restrict__ x_pre,
    float* __restrict__ out_topv,
    float* __restrict__ out_nidx)
{
    const int lane  = threadIdx.x & 63;
    const int wslot = threadIdx.x >> 6;

    // ---- XCD-aware bijective work swizzle ----
    const int n  = blockIdx.x;           // 0..12287
    const int x  = n & 7;                // XCD (HW: round-robin n%8)
    const int r  = n >> 3;               // 0..1535
    const int bq = r / 384;              // 0..3
    const int wb = r - bq * 384;         // 0..383
    const int b  = x * 4 + bq;           // window clustered per XCD
    const int row = b * (H_ * N_) + wb * 4 + wslot;

    const int rem = row - b * (H_ * N_);
    const int h   = rem / N_;
    const int i   = rem - h * N_;

    const int row_off = row * TKIN;
    const int idx  = pfa_index[row_off + lane];
    const float pv = pfa_values[row_off + lane];

    __shared__ uint2  s_pk[4][64];    // packed (bits<<6)|(63-lane)
    __shared__ double s_k64[4][64];   // okey (slow path only)
    __shared__ float  s_a[4][TKOUT];
    __shared__ int    s_i[4][TKOUT];

    const float* qp = qkvp + (size_t)(b * N_ + i) * C4_ + h * HD_;
    const float* kp = qkvp + (size_t)(b * N_ + idx) * C4_ + C_ + h * HD_;
    const float bias = rpb_table[rpi[i * N_ + idx] * H_ + h];

    // ---- f32 chain: sequential no-FMA dot (bit-exact canonical) ----
    float acc;
    {
        #pragma clang fp contract(off)
        const float SC = 0.17677669529663687f;
        acc = 0.f;
        for (int d = 0; d < HD_; ++d) {
            const float qd   = qp[d] * SC;
            const float prod = qd * kp[d];
            acc = acc + prod;
        }
        acc = acc + bias;
    }

    // ---- f32 row max (exact, order-independent) ----
    float m = acc;
    #pragma unroll
    for (int s = 32; s; s >>= 1) m = fmaxf(m, __shfl_xor(m, s));

    // ---- e = exp(acc - m), correctly-rounded f32 via double ----
    float e;
    {
        #pragma clang fp contract(off)
        const float t = acc - m;
        e = (float)exp((double)t);
    }

    // ---- ssum: numpy pairwise-8 via shuffles (bit-exact, R22) ----
    float ssum;
    {
        #pragma clang fp contract(off)
        float y = e, r2 = e;
        #pragma unroll
        for (int k = 1; k < 8; ++k) { y = __shfl_down(y, 8); r2 = r2 + y; }
        const float t1 = r2 + __shfl_xor(r2, 1);
        const float t2 = t1 + __shfl_xor(t1, 2);
        const float t3 = t2 + __shfl_xor(t2, 4);
        ssum = __shfl(t3, 0);
    }

    // ---- w = (e/ssum)*pv ----
    float w;
    {
        #pragma clang fp contract(off)
        const float s32 = e / ssum;
        w = s32 * pv;
    }

    // ---- denom: same shuffle pairwise-8 over w ----
    float denom;
    {
        #pragma clang fp contract(off)
        float y = w, r2 = w;
        #pragma unroll
        for (int k = 1; k < 8; ++k) { y = __shfl_down(y, 8); r2 = r2 + y; }
        const float t1 = r2 + __shfl_xor(r2, 1);
        const float t2 = t1 + __shfl_xor(t1, 2);
        const float t3 = t2 + __shfl_xor(t2, 4);
        denom = __shfl(t3, 0);
    }

    // ---- a32 = (w + EPS)/(denom + EPS) ----
    float a32;
    {
        #pragma clang fp contract(off)
        a32 = (w + 1e-20f) / (denom + 1e-20f);
    }

    // ---- publish packed key ----
    const unsigned abits = __float_as_uint(a32);
    const unsigned long long myK =
        ((unsigned long long)abits << 6) | (unsigned long long)(63 - lane);
    s_pk[wslot][lane] = make_uint2((unsigned)myK, (unsigned)(myK >> 32));
    // no barrier: per-wave LDS slice; lgkmcnt orders RAW within the wave

    // ---- pass 1: rank via single u64 compare per j ----
    int rank = 0;
    #pragma unroll
    for (int j = 0; j < 64; ++j) {
        const uint2 kj = s_pk[wslot][j];
        const unsigned long long K =
            ((unsigned long long)kj.y << 32) | (unsigned long long)kj.x;
        rank += (K > myK);
    }

    // ---- near detect: sorted adjacency via ds_permute ----
    {
        const int sorted = __builtin_amdgcn_ds_permute(rank << 2, (int)abits);
        const int nxt    = __shfl_down(sorted, 1);
        const unsigned gap = (unsigned)sorted - (unsigned)nxt;   // descending
        const bool nearf = (lane < 63) && (gap <= WULP);
        if (__any(nearf)) {
            // ---- slow path (rare): okey comparator (R20/R25 verbatim) ----
            double acc64 = 0.0;
            #pragma unroll
            for (int d0 = 0; d0 < 8; ++d0) {
                const float4 q4 = *(const float4*)(qp + 4 * d0);
                const float4 k4 = *(const float4*)(kp + 4 * d0);
                acc64 = fma((double)q4.x, (double)k4.x, acc64);
                acc64 = fma((double)q4.y, (double)k4.y, acc64);
                acc64 = fma((double)q4.z, (double)k4.z, acc64);
                acc64 = fma((double)q4.w, (double)k4.w, acc64);
            }
            acc64 = acc64 * 0.17677669529663687 + (double)bias;
            const double okey = exp(acc64) * (double)pv;
            s_k64[wslot][lane] = okey;

            rank = 0;
            #pragma unroll
            for (int j = 0; j < 64; ++j) {
                const uint2 kj = s_pk[wslot][j];
                const unsigned kbits = (kj.y << 26) | (kj.x >> 6);
                const float  kj32 = __uint_as_float(kbits);
                const double kj64 = s_k64[wslot][j];
                const bool tie  = (kj32 == a32);
                const bool lt64 = (kj64 < okey);
                const bool gt64 = (kj64 > okey);
                const bool eq64 = (kj64 == okey);
                const bool before = tie ? (lt64 || (eq64 && j < lane))
                                        : (gt64 || (eq64 && kj32 > a32));
                rank += before;
            }
        }
    }

    if (rank < TKOUT) {
        const size_t obase = (size_t)row * TKOUT + rank;
        out_topv[obase] = a32;
        out_nidx[obase] = (float)idx;
        s_a[wslot][rank] = a32;
        s_i[wslot][rank] = idx;
    }

    // ---- PV (broadcast reads of own wave's compacted slots) ----
    const int d    = lane & 31;
    const int half = lane >> 5;
    float xd = 0.f;
    #pragma unroll
    for (int s16 = 0; s16 < 16; ++s16) {
        const int sI = half * 16 + s16;
        const float av = s_a[wslot][sI];
        const int   vi = s_i[wslot][sI];
        xd += av * qkvp[(size_t)(b * N_ + vi) * C4_ + 2 * C_ + h * HD_ + d];
    }
    xd += __shfl_xor(xd, 32);
    if (half == 0) {
        const float lepe = qkvp[(size_t)(b * N_ + i) * C4_ + 3 * C_ + h * HD_ + d];
        x_pre[(size_t)(b * N_ + i) * C_ + h * HD_ + d] = xd + lepe;
    }
}

// ---------------------------------------------------------------------------
#define TB_ 8
__global__ __launch_bounds__(192) void proj_kernel(
    const float* __restrict__ x_pre,
    const float* __restrict__ w,
    const float* __restrict__ bias,
    float* __restrict__ out)
{
    __shared__ float xs[TB_ * C_];
    const int o    = threadIdx.x;
    const int tok0 = blockIdx.x * TB_;

    #pragma unroll
    for (int r = 0; r < TB_; ++r)
        xs[r * C_ + o] = x_pre[(size_t)(tok0 + r) * C_ + o];
    __syncthreads();

    float accv[TB_];
    #pragma unroll
    for (int t = 0; t < TB_; ++t) accv[t] = 0.f;

    const float* wrow = w + (size_t)o * C_;
    for (int c = 0; c < C_; c += 4) {
        const float4 wv = *(const float4*)(wrow + c);
        #pragma unroll
        for (int t = 0; t < TB_; ++t) {
            const float4 xv = *(const float4*)(&xs[t * C_ + c]);
            accv[t] += xv.x * wv.x + xv.y * wv.y + xv.z * wv.z + xv.w * wv.w;
        }
    }
    const float bo = bias[o];
    #pragma unroll
    for (int t = 0; t < TB_; ++t)
        out[(size_t)(tok0 + t) * C_ + o] = accv[t] + bo;
}

// ---------------------------------------------------------------------------
extern "C" void kernel_launch(void* const* d_in, const int* in_sizes, int n_in,
                              void* d_out, int out_size, void* d_ws, size_t ws_size,
                              hipStream_t stream) {
    const float* qkvp       = (const float*)d_in[0];
    const float* pfa_values = (const float*)d_in[1];
    const int*   pfa_index  = (const int*)d_in[2];
    const int*   rpi        = (const int*)d_in[3];
    const float* rpb_table  = (const float*)d_in[4];
    const float* proj_w     = (const float*)d_in[5];
    const float* proj_b     = (const float*)d_in[6];

    float* out = (float*)d_out;
    float* out_x    = out;
    float* out_topv = out + (size_t)B_ * N_ * C_;
    float* out_nidx = out_topv + (size_t)B_ * H_ * N_ * TKOUT;

    float* x_pre = (float*)d_ws;

    const int rows = B_ * H_ * N_;                       // 49152
    attn_topk_kernel<<<rows / 4, 256, 0, stream>>>(
        qkvp, pfa_values, pfa_index, rpi, rpb_table, x_pre, out_topv, out_nidx);

    const int ntok = B_ * N_;                            // 8192
    proj_kernel<<<ntok / TB_, 192, 0, stream>>>(x_pre, proj_w, proj_b, out_x);
}